// Round 13
// baseline (624.695 us; speedup 1.0000x reference)
//
#include <hip/hip_runtime.h>

#define T_SEQ  2048
#define HID    4096
#define NQH    32
#define NKVH   8
#define HDIM   128

typedef float  f32x4  __attribute__((ext_vector_type(4)));
typedef __bf16 bf16x8 __attribute__((ext_vector_type(8)));

__device__ __forceinline__ float bf2f(unsigned short u) {
  union { unsigned int i; float f; } v; v.i = ((unsigned int)u) << 16; return v.f;
}
__device__ __forceinline__ unsigned short f2bf(float f) {
  union { float f; unsigned int i; } v; v.f = f;
  unsigned int r = v.i + 0x7fffu + ((v.i >> 16) & 1u);
  return (unsigned short)(r >> 16);
}

__device__ __forceinline__ f32x4 mfma_bf16(bf16x8 a, bf16x8 b, f32x4 c) {
  return __builtin_amdgcn_mfma_f32_16x16x32_bf16(a, b, c, 0, 0, 0);
}

#define GLOAD16(g, l)                                              \
  __builtin_amdgcn_global_load_lds(                                \
      (const __attribute__((address_space(1))) void*)(g),          \
      (__attribute__((address_space(3))) void*)(l), 16, 0, 0)

// ---------------------------------------------------------------- fused convert + wq transpose
// blocks [0, 8192): hs fp32 -> hb bf16 ; blocks [8192, 12288): wq -> wt transposed bf16
__global__ void prep_qw(const float* __restrict__ hs, unsigned short* __restrict__ hb,
                        const float* __restrict__ wq, unsigned short* __restrict__ wt) {
  __shared__ float tile[64][65];
  if (blockIdx.x < 8192) {
    long long i = ((long long)blockIdx.x * 256 + threadIdx.x) * 4;
    float4 v = *(const float4*)(hs + i);
    union { unsigned short u[4]; uint2 p; } o;
    o.u[0] = f2bf(v.x); o.u[1] = f2bf(v.y); o.u[2] = f2bf(v.z); o.u[3] = f2bf(v.w);
    *(uint2*)(hb + i) = o.p;
    return;
  }
  const int bid = blockIdx.x - 8192;
  const int N = NQH * HDIM, K = HID;
  int n0 = (bid & 63) * 64, k0 = (bid >> 6) * 64;
  int tx = threadIdx.x & 15, ty = threadIdx.x >> 4;
#pragma unroll
  for (int i = 0; i < 4; i++) {
    int k = ty + 16 * i;
    float4 f = *(const float4*)(wq + (long long)(k0 + k) * N + n0 + tx * 4);
    tile[tx * 4 + 0][k] = f.x;
    tile[tx * 4 + 1][k] = f.y;
    tile[tx * 4 + 2][k] = f.z;
    tile[tx * 4 + 3][k] = f.w;
  }
  __syncthreads();
#pragma unroll
  for (int i = 0; i < 4; i++) {
    int n = ty + 16 * i;
    union { unsigned short u[4]; uint2 p; } o;
    o.u[0] = f2bf(tile[n][tx * 4 + 0]);
    o.u[1] = f2bf(tile[n][tx * 4 + 1]);
    o.u[2] = f2bf(tile[n][tx * 4 + 2]);
    o.u[3] = f2bf(tile[n][tx * 4 + 3]);
    *(uint2*)(wt + (long long)(n0 + n) * K + k0 + tx * 4) = o.p;
  }
}

// ---------------------------------------------------------------- transpose v2: 64x64 tile, vectorized
__global__ void transpose_conv(const float* __restrict__ W,
                               unsigned short* __restrict__ Wt, int K, int N) {
  __shared__ float tile[64][65];
  int n0 = blockIdx.x * 64, k0 = blockIdx.y * 64;
  int tx = threadIdx.x & 15, ty = threadIdx.x >> 4;
#pragma unroll
  for (int i = 0; i < 4; i++) {
    int k = ty + 16 * i;
    float4 f = *(const float4*)(W + (long long)(k0 + k) * N + n0 + tx * 4);
    tile[tx * 4 + 0][k] = f.x;
    tile[tx * 4 + 1][k] = f.y;
    tile[tx * 4 + 2][k] = f.z;
    tile[tx * 4 + 3][k] = f.w;
  }
  __syncthreads();
#pragma unroll
  for (int i = 0; i < 4; i++) {
    int n = ty + 16 * i;
    union { unsigned short u[4]; uint2 p; } o;
    o.u[0] = f2bf(tile[n][tx * 4 + 0]);
    o.u[1] = f2bf(tile[n][tx * 4 + 1]);
    o.u[2] = f2bf(tile[n][tx * 4 + 2]);
    o.u[3] = f2bf(tile[n][tx * 4 + 3]);
    *(uint2*)(Wt + (long long)(n0 + n) * K + k0 + tx * 4) = o.p;
  }
}

// fused wk+wv transpose
__global__ void transpose_conv_kv(const float* __restrict__ Wk,
                                  const float* __restrict__ Wv,
                                  unsigned short* __restrict__ Wt) {
  __shared__ float tile[64][65];
  const int N = NKVH * HDIM, K = HID;
  const float* W = blockIdx.z ? Wv : Wk;
  unsigned short* dst = Wt + (size_t)blockIdx.z * N * K;
  int n0 = blockIdx.x * 64, k0 = blockIdx.y * 64;
  int tx = threadIdx.x & 15, ty = threadIdx.x >> 4;
#pragma unroll
  for (int i = 0; i < 4; i++) {
    int k = ty + 16 * i;
    float4 f = *(const float4*)(W + (long long)(k0 + k) * N + n0 + tx * 4);
    tile[tx * 4 + 0][k] = f.x;
    tile[tx * 4 + 1][k] = f.y;
    tile[tx * 4 + 2][k] = f.z;
    tile[tx * 4 + 3][k] = f.w;
  }
  __syncthreads();
#pragma unroll
  for (int i = 0; i < 4; i++) {
    int n = ty + 16 * i;
    union { unsigned short u[4]; uint2 p; } o;
    o.u[0] = f2bf(tile[n][tx * 4 + 0]);
    o.u[1] = f2bf(tile[n][tx * 4 + 1]);
    o.u[2] = f2bf(tile[n][tx * 4 + 2]);
    o.u[3] = f2bf(tile[n][tx * 4 + 3]);
    *(uint2*)(dst + (long long)(n0 + n) * K + k0 + tx * 4) = o.p;
  }
}

// ---------------------------------------------------------------- GEMM v2: BK=64 + LDS XOR swizzle + XCD swizzle
template <int EPI>
__global__ __launch_bounds__(256) void gemm_bt(const unsigned short* __restrict__ A,
                                               const unsigned short* __restrict__ Bt,
                                               void* __restrict__ Cv,
                                               int M, int N, int K) {
  __shared__ unsigned short As[128 * 64];
  __shared__ unsigned short Bs[128 * 64];
  const int lin = blockIdx.y * gridDim.x + blockIdx.x;
  const int cpx = (gridDim.x * gridDim.y) >> 3;
  const int swz = (lin & 7) * cpx + (lin >> 3);
  const int bx = swz % gridDim.x, by = swz / gridDim.x;

  const int t = threadIdx.x;
  const int lane = t & 63, w = t >> 6;
  const int wr = w >> 1, wc = w & 1;
  const int l15 = lane & 15, lg = lane >> 4;
  const int m0 = by * 128, n0 = bx * 128;

  f32x4 acc[4][4];
#pragma unroll
  for (int i = 0; i < 4; i++)
#pragma unroll
    for (int j = 0; j < 4; j++) acc[i][j] = (f32x4){0.f, 0.f, 0.f, 0.f};

  for (int kt = 0; kt < K; kt += 64) {
    __syncthreads();
#pragma unroll
    for (int s = 0; s < 4; s++) {
      int c = t + s * 256;
      int row = c >> 3, sub = c & 7;
      GLOAD16(A + (long long)(m0 + row) * K + kt + ((sub ^ (row & 7)) * 8),
              (char*)As + (w * 64 + s * 256) * 16);
      GLOAD16(Bt + (long long)(n0 + row) * K + kt + ((sub ^ (row & 7)) * 8),
              (char*)Bs + (w * 64 + s * 256) * 16);
    }
    __syncthreads();

#pragma unroll
    for (int kk = 0; kk < 2; kk++) {
      bf16x8 af[4], bfr[4];
#pragma unroll
      for (int mi = 0; mi < 4; mi++) {
        int row = wr * 64 + mi * 16 + l15;
        af[mi] = *(const bf16x8*)(As + row * 64 + (((kk * 4 + lg) ^ (row & 7)) * 8));
      }
#pragma unroll
      for (int ni = 0; ni < 4; ni++) {
        int row = wc * 64 + ni * 16 + l15;
        bfr[ni] = *(const bf16x8*)(Bs + row * 64 + (((kk * 4 + lg) ^ (row & 7)) * 8));
      }
#pragma unroll
      for (int mi = 0; mi < 4; mi++)
#pragma unroll
        for (int ni = 0; ni < 4; ni++)
          acc[mi][ni] = mfma_bf16(af[mi], bfr[ni], acc[mi][ni]);
    }
  }

  const int row0 = m0 + wr * 64, col0 = n0 + wc * 64;
#pragma unroll
  for (int mi = 0; mi < 4; mi++)
#pragma unroll
    for (int ni = 0; ni < 4; ni++) {
      int rbase = row0 + mi * 16 + lg * 4;
      int col = col0 + ni * 16 + l15;
#pragma unroll
      for (int r = 0; r < 4; r++) {
        float v = acc[mi][ni][r];
        if (EPI == 0)
          ((unsigned short*)Cv)[(long long)(rbase + r) * N + col] = f2bf(v);
        else
          ((float*)Cv)[(long long)(rbase + r) * N + col] = v;
      }
    }
}

// ---------------------------------------------------------------- KV GEMM v2: BM=64, BK=64 + XOR swizzle
__global__ __launch_bounds__(256) void gemm_kv64(const unsigned short* __restrict__ A,
                                                 const unsigned short* __restrict__ Bt,
                                                 unsigned short* __restrict__ Ckv,
                                                 unsigned short* __restrict__ Cvt) {
  __shared__ unsigned short As[64 * 64];
  __shared__ unsigned short Bs[128 * 64];
  __shared__ unsigned short Tt[128 * 64];
  const int lin = blockIdx.y * gridDim.x + blockIdx.x;
  const int swz = (lin & 7) * 64 + (lin >> 3);
  const int bx = swz & 15, by = swz >> 4;

  const int t = threadIdx.x;
  const int lane = t & 63, w = t >> 6;
  const int wr = w >> 1, wc = w & 1;
  const int l15 = lane & 15, lg = lane >> 4;
  const int m0 = by * 64, n0 = bx * 128;
  const int K = HID;

  f32x4 acc[2][4];
#pragma unroll
  for (int i = 0; i < 2; i++)
#pragma unroll
    for (int j = 0; j < 4; j++) acc[i][j] = (f32x4){0.f, 0.f, 0.f, 0.f};

  for (int kt = 0; kt < K; kt += 64) {
    __syncthreads();
#pragma unroll
    for (int s = 0; s < 2; s++) {
      int c = t + s * 256;
      int row = c >> 3, sub = c & 7;
      GLOAD16(A + (long long)(m0 + row) * K + kt + ((sub ^ (row & 7)) * 8),
              (char*)As + (w * 64 + s * 256) * 16);
    }
#pragma unroll
    for (int s = 0; s < 4; s++) {
      int c = t + s * 256;
      int row = c >> 3, sub = c & 7;
      GLOAD16(Bt + (long long)(n0 + row) * K + kt + ((sub ^ (row & 7)) * 8),
              (char*)Bs + (w * 64 + s * 256) * 16);
    }
    __syncthreads();

#pragma unroll
    for (int kk = 0; kk < 2; kk++) {
      bf16x8 af[2], bfr[4];
#pragma unroll
      for (int mi = 0; mi < 2; mi++) {
        int row = wr * 32 + mi * 16 + l15;
        af[mi] = *(const bf16x8*)(As + row * 64 + (((kk * 4 + lg) ^ (row & 7)) * 8));
      }
#pragma unroll
      for (int ni = 0; ni < 4; ni++) {
        int row = wc * 64 + ni * 16 + l15;
        bfr[ni] = *(const bf16x8*)(Bs + row * 64 + (((kk * 4 + lg) ^ (row & 7)) * 8));
      }
#pragma unroll
      for (int mi = 0; mi < 2; mi++)
#pragma unroll
        for (int ni = 0; ni < 4; ni++)
          acc[mi][ni] = mfma_bf16(af[mi], bfr[ni], acc[mi][ni]);
    }
  }

  const int row0 = m0 + wr * 32, col0 = n0 + wc * 64;
  if (n0 < 1024) {
#pragma unroll
    for (int mi = 0; mi < 2; mi++)
#pragma unroll
      for (int ni = 0; ni < 4; ni++) {
        int rbase = row0 + mi * 16 + lg * 4;
        int col = col0 + ni * 16 + l15;
#pragma unroll
        for (int r = 0; r < 4; r++)
          Ckv[(long long)(rbase + r) * 1024 + col] = f2bf(acc[mi][ni][r]);
      }
  } else {
#pragma unroll
    for (int mi = 0; mi < 2; mi++)
#pragma unroll
      for (int ni = 0; ni < 4; ni++) {
        int nloc = wc * 64 + ni * 16 + l15;
#pragma unroll
        for (int r = 0; r < 4; r++) {
          int mloc = wr * 32 + mi * 16 + lg * 4 + r;
          Tt[nloc * 64 + (mloc ^ ((nloc & 7) << 3))] = f2bf(acc[mi][ni][r]);
        }
      }
    __syncthreads();
    const int nloc = t >> 1;
#pragma unroll
    for (int cc = 0; cc < 4; cc++) {
      int ci = (t & 1) * 4 + cc;
      int sc = ci ^ (nloc & 7);
      uint4 v = *(const uint4*)(Tt + nloc * 64 + sc * 8);
      *(uint4*)(Cvt + (long long)(n0 - 1024 + nloc) * T_SEQ + m0 + ci * 8) = v;
    }
  }
}

// ---------------------------------------------------------------- RoPE (neox, fp64 angles), fused q+k
__global__ void rope_all(unsigned short* __restrict__ qb,
                         unsigned short* __restrict__ kb,
                         const int* __restrict__ positions) {
  const int w = threadIdx.x >> 6, d = threadIdx.x & 63;
  const int gid = blockIdx.x * 4 + w;
  unsigned short* row;
  int t;
  bool isq;
  if (gid < T_SEQ * NQH) {
    int h = gid & (NQH - 1); t = gid >> 5;
    row = qb + (size_t)t * (NQH * HDIM) + (size_t)h * HDIM;
    isq = true;
  } else {
    int g = gid - T_SEQ * NQH;
    int h = g & (NKVH - 1); t = g >> 3;
    row = kb + (size_t)t * (NKVH * HDIM) + (size_t)h * HDIM;
    isq = false;
  }
  double inv = exp2(-(double)d * 0.20762050593046014);
  double ang = (double)positions[t] * inv;
  double c = cos(ang), s = sin(ang);
  if (isq) { c *= 0.12751744416986895; s *= 0.12751744416986895; }
  float x1 = bf2f(row[d]), x2 = bf2f(row[d + 64]);
  row[d]      = f2bf((float)((double)x1 * c - (double)x2 * s));
  row[d + 64] = f2bf((float)((double)x2 * c + (double)x1 * s));
}

// ---------------------------------------------------------------- flash attention v8: NO K/V staging
// K/V fragments read directly from global (L2-resident: 1 kv-head per XCD = 1MB << 4MB L2).
// No __syncthreads in the loop — waves fully independent. LDS = P only (8KB).
__global__ __launch_bounds__(256) void attn_kernel(const unsigned short* __restrict__ qb,
                                                   const unsigned short* __restrict__ kb,
                                                   const unsigned short* __restrict__ vt,
                                                   unsigned short* __restrict__ ab) {
  __shared__ unsigned short Ps[4][16 * 64];

  const int lin = blockIdx.y * gridDim.x + blockIdx.x;  // 0..1023
  const int swz = (lin & 7) * 128 + (lin >> 3);
  const int bx = swz & 31;
  const int h  = swz >> 5;
  const int kvh = h >> 2;
  const int j  = (h & 1) ? bx : 31 - bx;  // zigzag balance
  const int q0 = j * 64;
  const int t = threadIdx.x, lane = t & 63, w = t >> 6;
  const int l15 = lane & 15, lg = lane >> 4;

  // per-lane fixed bases into K and V^T
  const unsigned short* kbase = kb + (size_t)l15 * (NKVH * HDIM) + kvh * HDIM + lg * 8;
  const unsigned short* vbase = vt + (size_t)(kvh * HDIM + l15) * T_SEQ + lg * 8;

  bf16x8 qf[4];
#pragma unroll
  for (int kk = 0; kk < 4; kk++)
    qf[kk] = *(const bf16x8*)(qb + (long long)(q0 + w * 16 + l15) * (NQH * HDIM) +
                              h * HDIM + kk * 32 + lg * 8);

  f32x4 accO[8];
#pragma unroll
  for (int db = 0; db < 8; db++) accO[db] = (f32x4){0.f, 0.f, 0.f, 0.f};
  float mrun[4] = {-3e38f, -3e38f, -3e38f, -3e38f};
  float lrun[4] = {0.f, 0.f, 0.f, 0.f};

  const int nt = j + 1;
  for (int kt = 0; kt < nt; kt++) {
    // S = Q K^T : 16 q-rows x 64 k-cols; K fragments direct from L2
    f32x4 accS[4];
#pragma unroll
    for (int kc = 0; kc < 4; kc++) accS[kc] = (f32x4){0.f, 0.f, 0.f, 0.f};
    __builtin_amdgcn_s_setprio(1);
#pragma unroll
    for (int kc = 0; kc < 4; kc++) {
      const unsigned short* kr = kbase + (size_t)(kt * 64 + kc * 16) * (NKVH * HDIM);
      bf16x8 kf[4];
#pragma unroll
      for (int kk = 0; kk < 4; kk++)
        kf[kk] = *(const bf16x8*)(kr + kk * 32);
#pragma unroll
      for (int kk = 0; kk < 4; kk++)
        accS[kc] = mfma_bf16(qf[kk], kf[kk], accS[kc]);
    }
    __builtin_amdgcn_s_setprio(0);

    // causal mask only on the diagonal tile
    float pm[4][4];
    if (kt == j) {
#pragma unroll
      for (int kc = 0; kc < 4; kc++) {
        int kcl = kc * 16 + l15;
#pragma unroll
        for (int r = 0; r < 4; r++)
          pm[kc][r] = (kcl > w * 16 + lg * 4 + r) ? -3e38f : accS[kc][r];
      }
    } else {
#pragma unroll
      for (int kc = 0; kc < 4; kc++)
#pragma unroll
        for (int r = 0; r < 4; r++) pm[kc][r] = accS[kc][r];
    }

    // lane-local max; __any-gated full reduce + rescale (defer-max THR=8)
    float rm[4];
#pragma unroll
    for (int r = 0; r < 4; r++)
      rm[r] = fmaxf(fmaxf(pm[0][r], pm[1][r]), fmaxf(pm[2][r], pm[3][r]));
    int needl = 0;
#pragma unroll
    for (int r = 0; r < 4; r++) needl |= (rm[r] > mrun[r] + 8.f) ? 1 : 0;
    if (__any(needl)) {
#pragma unroll
      for (int off = 1; off < 16; off <<= 1)
#pragma unroll
        for (int r = 0; r < 4; r++) rm[r] = fmaxf(rm[r], __shfl_xor(rm[r], off, 64));
#pragma unroll
      for (int r = 0; r < 4; r++) {
        float mn = fmaxf(mrun[r], rm[r]);
        float corr = exp2f(mrun[r] - mn);
        mrun[r] = mn;
        lrun[r] *= corr;
#pragma unroll
        for (int db = 0; db < 8; db++) accO[db][r] *= corr;
      }
    }

    // P = exp2(pm - mrun); per-lane partial row-sum
    __bf16 pbh[4][4];
#pragma unroll
    for (int kc = 0; kc < 4; kc++)
#pragma unroll
      for (int r = 0; r < 4; r++) {
        float p = exp2f(pm[kc][r] - mrun[r]);
        lrun[r] += p;
        pbh[kc][r] = (__bf16)p;
      }

    // P -> LDS (wave-private [16][64], 8-elem-chunk XOR (row&7))
    unsigned short* Pw = &Ps[w][0];
#pragma unroll
    for (int kc = 0; kc < 4; kc++)
#pragma unroll
      for (int r = 0; r < 4; r++) {
        int prow = lg * 4 + r;
        ((__bf16*)Pw)[(prow * 64 + kc * 16 + l15) ^ ((prow & 7) << 3)] = pbh[kc][r];
      }
    asm volatile("s_waitcnt lgkmcnt(0)" ::: "memory");

    // O += P * V ; V fragments direct from L2
    __builtin_amdgcn_s_setprio(1);
#pragma unroll
    for (int ks = 0; ks < 2; ks++) {
      bf16x8 pa = *(const bf16x8*)(Pw + ((l15 * 64 + ks * 32 + lg * 8) ^ ((l15 & 7) << 3)));
#pragma unroll
      for (int db = 0; db < 8; db++) {
        bf16x8 b = *(const bf16x8*)(vbase + (size_t)db * 16 * T_SEQ + kt * 64 + ks * 32);
        accO[db] = mfma_bf16(pa, b, accO[db]);
      }
    }
    __builtin_amdgcn_s_setprio(0);
  }

  // epilogue
#pragma unroll
  for (int off = 1; off < 16; off <<= 1)
#pragma unroll
    for (int r = 0; r < 4; r++) lrun[r] += __shfl_xor(lrun[r], off, 64);
#pragma unroll
  for (int db = 0; db < 8; db++)
#pragma unroll
    for (int r = 0; r < 4; r++) {
      int qr = q0 + w * 16 + lg * 4 + r;
      int col = h * HDIM + db * 16 + l15;
      ((__bf16*)ab)[(long long)qr * (NQH * HDIM) + col] = (__bf16)(accO[db][r] / lrun[r]);
    }
}

// ---------------------------------------------------------------- launch
extern "C" void kernel_launch(void* const* d_in, const int* in_sizes, int n_in,
                              void* d_out, int out_size, void* d_ws, size_t ws_size,
                              hipStream_t stream) {
  const int*   positions = (const int*)d_in[0];
  const float* hs = (const float*)d_in[1];
  const float* wq = (const float*)d_in[2];
  const float* wk = (const float*)d_in[3];
  const float* wv = (const float*)d_in[4];
  const float* wo = (const float*)d_in[5];
  float* out = (float*)d_out;

  const size_t SZ_WT = (size_t)HID * HID * 2;
  const size_t SZ_HB = (size_t)T_SEQ * HID * 2;
  const size_t SZ_QB = (size_t)T_SEQ * NQH * HDIM * 2;
  const size_t SZ_KB = (size_t)T_SEQ * NKVH * HDIM * 2;
  const size_t need = SZ_WT + SZ_HB + SZ_QB + SZ_KB * 2;
  if (ws_size < need) return;  // absmax 4.625 signature

  char* p = (char*)d_ws;
  unsigned short* wt  = (unsigned short*)p; p += SZ_WT;
  unsigned short* hb  = (unsigned short*)p; p += SZ_HB;
  unsigned short* qb  = (unsigned short*)p; p += SZ_QB;
  unsigned short* kb  = (unsigned short*)p; p += SZ_KB;
  unsigned short* vtb = (unsigned short*)p; p += SZ_KB;
  unsigned short* ab  = hb;  // alias: hb dead after KV-GEMM

  // fused: hidden convert + wq transpose
  prep_qw<<<8192 + 4096, 256, 0, stream>>>(hs, hb, wq, wt);
  gemm_bt<0><<<dim3((NQH * HDIM) / 128, T_SEQ / 128), 256, 0, stream>>>(hb, wt, qb, T_SEQ, NQH * HDIM, HID);

  transpose_conv_kv<<<dim3((NKVH * HDIM) / 64, HID / 64, 2), 256, 0, stream>>>(wk, wv, wt);
  gemm_kv64<<<dim3(16, 32), 256, 0, stream>>>(hb, wt, kb, vtb);

  rope_all<<<(T_SEQ * (NQH + NKVH)) / 4, 256, 0, stream>>>(qb, kb, positions);

  attn_kernel<<<dim3(32, 32), 256, 0, stream>>>(qb, kb, vtb, ab);

  transpose_conv<<<dim3(HID / 64, (NQH * HDIM) / 64), 256, 0, stream>>>(wo, wt, NQH * HDIM, HID);
  gemm_bt<2><<<dim3(HID / 128, T_SEQ / 128), 256, 0, stream>>>(ab, wt, out, T_SEQ, HID, NQH * HDIM);
}

// Round 14
// 391.147 us; speedup vs baseline: 1.5971x; 1.5971x over previous
//
#include <hip/hip_runtime.h>

#define T_SEQ  2048
#define HID    4096
#define NQH    32
#define NKVH   8
#define HDIM   128

typedef float  f32x4  __attribute__((ext_vector_type(4)));
typedef __bf16 bf16x8 __attribute__((ext_vector_type(8)));

__device__ __forceinline__ float bf2f(unsigned short u) {
  union { unsigned int i; float f; } v; v.i = ((unsigned int)u) << 16; return v.f;
}
__device__ __forceinline__ unsigned short f2bf(float f) {
  union { float f; unsigned int i; } v; v.f = f;
  unsigned int r = v.i + 0x7fffu + ((v.i >> 16) & 1u);
  return (unsigned short)(r >> 16);
}

__device__ __forceinline__ f32x4 mfma_bf16(bf16x8 a, bf16x8 b, f32x4 c) {
  return __builtin_amdgcn_mfma_f32_16x16x32_bf16(a, b, c, 0, 0, 0);
}

#define GLOAD16(g, l)                                              \
  __builtin_amdgcn_global_load_lds(                                \
      (const __attribute__((address_space(1))) void*)(g),          \
      (__attribute__((address_space(3))) void*)(l), 16, 0, 0)

// ---------------------------------------------------------------- fused convert + wq transpose
__global__ void prep_qw(const float* __restrict__ hs, unsigned short* __restrict__ hb,
                        const float* __restrict__ wq, unsigned short* __restrict__ wt) {
  __shared__ float tile[64][65];
  if (blockIdx.x < 8192) {
    long long i = ((long long)blockIdx.x * 256 + threadIdx.x) * 4;
    float4 v = *(const float4*)(hs + i);
    union { unsigned short u[4]; uint2 p; } o;
    o.u[0] = f2bf(v.x); o.u[1] = f2bf(v.y); o.u[2] = f2bf(v.z); o.u[3] = f2bf(v.w);
    *(uint2*)(hb + i) = o.p;
    return;
  }
  const int bid = blockIdx.x - 8192;
  const int N = NQH * HDIM, K = HID;
  int n0 = (bid & 63) * 64, k0 = (bid >> 6) * 64;
  int tx = threadIdx.x & 15, ty = threadIdx.x >> 4;
#pragma unroll
  for (int i = 0; i < 4; i++) {
    int k = ty + 16 * i;
    float4 f = *(const float4*)(wq + (long long)(k0 + k) * N + n0 + tx * 4);
    tile[tx * 4 + 0][k] = f.x;
    tile[tx * 4 + 1][k] = f.y;
    tile[tx * 4 + 2][k] = f.z;
    tile[tx * 4 + 3][k] = f.w;
  }
  __syncthreads();
#pragma unroll
  for (int i = 0; i < 4; i++) {
    int n = ty + 16 * i;
    union { unsigned short u[4]; uint2 p; } o;
    o.u[0] = f2bf(tile[n][tx * 4 + 0]);
    o.u[1] = f2bf(tile[n][tx * 4 + 1]);
    o.u[2] = f2bf(tile[n][tx * 4 + 2]);
    o.u[3] = f2bf(tile[n][tx * 4 + 3]);
    *(uint2*)(wt + (long long)(n0 + n) * K + k0 + tx * 4) = o.p;
  }
}

// ---------------------------------------------------------------- transpose v2: 64x64 tile, vectorized
__global__ void transpose_conv(const float* __restrict__ W,
                               unsigned short* __restrict__ Wt, int K, int N) {
  __shared__ float tile[64][65];
  int n0 = blockIdx.x * 64, k0 = blockIdx.y * 64;
  int tx = threadIdx.x & 15, ty = threadIdx.x >> 4;
#pragma unroll
  for (int i = 0; i < 4; i++) {
    int k = ty + 16 * i;
    float4 f = *(const float4*)(W + (long long)(k0 + k) * N + n0 + tx * 4);
    tile[tx * 4 + 0][k] = f.x;
    tile[tx * 4 + 1][k] = f.y;
    tile[tx * 4 + 2][k] = f.z;
    tile[tx * 4 + 3][k] = f.w;
  }
  __syncthreads();
#pragma unroll
  for (int i = 0; i < 4; i++) {
    int n = ty + 16 * i;
    union { unsigned short u[4]; uint2 p; } o;
    o.u[0] = f2bf(tile[n][tx * 4 + 0]);
    o.u[1] = f2bf(tile[n][tx * 4 + 1]);
    o.u[2] = f2bf(tile[n][tx * 4 + 2]);
    o.u[3] = f2bf(tile[n][tx * 4 + 3]);
    *(uint2*)(Wt + (long long)(n0 + n) * K + k0 + tx * 4) = o.p;
  }
}

// fused wk+wv transpose
__global__ void transpose_conv_kv(const float* __restrict__ Wk,
                                  const float* __restrict__ Wv,
                                  unsigned short* __restrict__ Wt) {
  __shared__ float tile[64][65];
  const int N = NKVH * HDIM, K = HID;
  const float* W = blockIdx.z ? Wv : Wk;
  unsigned short* dst = Wt + (size_t)blockIdx.z * N * K;
  int n0 = blockIdx.x * 64, k0 = blockIdx.y * 64;
  int tx = threadIdx.x & 15, ty = threadIdx.x >> 4;
#pragma unroll
  for (int i = 0; i < 4; i++) {
    int k = ty + 16 * i;
    float4 f = *(const float4*)(W + (long long)(k0 + k) * N + n0 + tx * 4);
    tile[tx * 4 + 0][k] = f.x;
    tile[tx * 4 + 1][k] = f.y;
    tile[tx * 4 + 2][k] = f.z;
    tile[tx * 4 + 3][k] = f.w;
  }
  __syncthreads();
#pragma unroll
  for (int i = 0; i < 4; i++) {
    int n = ty + 16 * i;
    union { unsigned short u[4]; uint2 p; } o;
    o.u[0] = f2bf(tile[n][tx * 4 + 0]);
    o.u[1] = f2bf(tile[n][tx * 4 + 1]);
    o.u[2] = f2bf(tile[n][tx * 4 + 2]);
    o.u[3] = f2bf(tile[n][tx * 4 + 3]);
    *(uint2*)(dst + (long long)(n0 + n) * K + k0 + tx * 4) = o.p;
  }
}

// ---------------------------------------------------------------- GEMM v2: BK=64 + LDS XOR swizzle + XCD swizzle
template <int EPI>
__global__ __launch_bounds__(256) void gemm_bt(const unsigned short* __restrict__ A,
                                               const unsigned short* __restrict__ Bt,
                                               void* __restrict__ Cv,
                                               int M, int N, int K) {
  __shared__ unsigned short As[128 * 64];
  __shared__ unsigned short Bs[128 * 64];
  const int lin = blockIdx.y * gridDim.x + blockIdx.x;
  const int cpx = (gridDim.x * gridDim.y) >> 3;
  const int swz = (lin & 7) * cpx + (lin >> 3);
  const int bx = swz % gridDim.x, by = swz / gridDim.x;

  const int t = threadIdx.x;
  const int lane = t & 63, w = t >> 6;
  const int wr = w >> 1, wc = w & 1;
  const int l15 = lane & 15, lg = lane >> 4;
  const int m0 = by * 128, n0 = bx * 128;

  f32x4 acc[4][4];
#pragma unroll
  for (int i = 0; i < 4; i++)
#pragma unroll
    for (int j = 0; j < 4; j++) acc[i][j] = (f32x4){0.f, 0.f, 0.f, 0.f};

  for (int kt = 0; kt < K; kt += 64) {
    __syncthreads();
#pragma unroll
    for (int s = 0; s < 4; s++) {
      int c = t + s * 256;
      int row = c >> 3, sub = c & 7;
      GLOAD16(A + (long long)(m0 + row) * K + kt + ((sub ^ (row & 7)) * 8),
              (char*)As + (w * 64 + s * 256) * 16);
      GLOAD16(Bt + (long long)(n0 + row) * K + kt + ((sub ^ (row & 7)) * 8),
              (char*)Bs + (w * 64 + s * 256) * 16);
    }
    __syncthreads();

#pragma unroll
    for (int kk = 0; kk < 2; kk++) {
      bf16x8 af[4], bfr[4];
#pragma unroll
      for (int mi = 0; mi < 4; mi++) {
        int row = wr * 64 + mi * 16 + l15;
        af[mi] = *(const bf16x8*)(As + row * 64 + (((kk * 4 + lg) ^ (row & 7)) * 8));
      }
#pragma unroll
      for (int ni = 0; ni < 4; ni++) {
        int row = wc * 64 + ni * 16 + l15;
        bfr[ni] = *(const bf16x8*)(Bs + row * 64 + (((kk * 4 + lg) ^ (row & 7)) * 8));
      }
#pragma unroll
      for (int mi = 0; mi < 4; mi++)
#pragma unroll
        for (int ni = 0; ni < 4; ni++)
          acc[mi][ni] = mfma_bf16(af[mi], bfr[ni], acc[mi][ni]);
    }
  }

  const int row0 = m0 + wr * 64, col0 = n0 + wc * 64;
#pragma unroll
  for (int mi = 0; mi < 4; mi++)
#pragma unroll
    for (int ni = 0; ni < 4; ni++) {
      int rbase = row0 + mi * 16 + lg * 4;
      int col = col0 + ni * 16 + l15;
#pragma unroll
      for (int r = 0; r < 4; r++) {
        float v = acc[mi][ni][r];
        if (EPI == 0)
          ((unsigned short*)Cv)[(long long)(rbase + r) * N + col] = f2bf(v);
        else
          ((float*)Cv)[(long long)(rbase + r) * N + col] = v;
      }
    }
}

// ---------------------------------------------------------------- KV GEMM v2: BM=64, BK=64 + XOR swizzle
__global__ __launch_bounds__(256) void gemm_kv64(const unsigned short* __restrict__ A,
                                                 const unsigned short* __restrict__ Bt,
                                                 unsigned short* __restrict__ Ckv,
                                                 unsigned short* __restrict__ Cvt) {
  __shared__ unsigned short As[64 * 64];
  __shared__ unsigned short Bs[128 * 64];
  __shared__ unsigned short Tt[128 * 64];
  const int lin = blockIdx.y * gridDim.x + blockIdx.x;
  const int swz = (lin & 7) * 64 + (lin >> 3);
  const int bx = swz & 15, by = swz >> 4;

  const int t = threadIdx.x;
  const int lane = t & 63, w = t >> 6;
  const int wr = w >> 1, wc = w & 1;
  const int l15 = lane & 15, lg = lane >> 4;
  const int m0 = by * 64, n0 = bx * 128;
  const int K = HID;

  f32x4 acc[2][4];
#pragma unroll
  for (int i = 0; i < 2; i++)
#pragma unroll
    for (int j = 0; j < 4; j++) acc[i][j] = (f32x4){0.f, 0.f, 0.f, 0.f};

  for (int kt = 0; kt < K; kt += 64) {
    __syncthreads();
#pragma unroll
    for (int s = 0; s < 2; s++) {
      int c = t + s * 256;
      int row = c >> 3, sub = c & 7;
      GLOAD16(A + (long long)(m0 + row) * K + kt + ((sub ^ (row & 7)) * 8),
              (char*)As + (w * 64 + s * 256) * 16);
    }
#pragma unroll
    for (int s = 0; s < 4; s++) {
      int c = t + s * 256;
      int row = c >> 3, sub = c & 7;
      GLOAD16(Bt + (long long)(n0 + row) * K + kt + ((sub ^ (row & 7)) * 8),
              (char*)Bs + (w * 64 + s * 256) * 16);
    }
    __syncthreads();

#pragma unroll
    for (int kk = 0; kk < 2; kk++) {
      bf16x8 af[2], bfr[4];
#pragma unroll
      for (int mi = 0; mi < 2; mi++) {
        int row = wr * 32 + mi * 16 + l15;
        af[mi] = *(const bf16x8*)(As + row * 64 + (((kk * 4 + lg) ^ (row & 7)) * 8));
      }
#pragma unroll
      for (int ni = 0; ni < 4; ni++) {
        int row = wc * 64 + ni * 16 + l15;
        bfr[ni] = *(const bf16x8*)(Bs + row * 64 + (((kk * 4 + lg) ^ (row & 7)) * 8));
      }
#pragma unroll
      for (int mi = 0; mi < 2; mi++)
#pragma unroll
        for (int ni = 0; ni < 4; ni++)
          acc[mi][ni] = mfma_bf16(af[mi], bfr[ni], acc[mi][ni]);
    }
  }

  const int row0 = m0 + wr * 32, col0 = n0 + wc * 64;
  if (n0 < 1024) {
#pragma unroll
    for (int mi = 0; mi < 2; mi++)
#pragma unroll
      for (int ni = 0; ni < 4; ni++) {
        int rbase = row0 + mi * 16 + lg * 4;
        int col = col0 + ni * 16 + l15;
#pragma unroll
        for (int r = 0; r < 4; r++)
          Ckv[(long long)(rbase + r) * 1024 + col] = f2bf(acc[mi][ni][r]);
      }
  } else {
#pragma unroll
    for (int mi = 0; mi < 2; mi++)
#pragma unroll
      for (int ni = 0; ni < 4; ni++) {
        int nloc = wc * 64 + ni * 16 + l15;
#pragma unroll
        for (int r = 0; r < 4; r++) {
          int mloc = wr * 32 + mi * 16 + lg * 4 + r;
          Tt[nloc * 64 + (mloc ^ ((nloc & 7) << 3))] = f2bf(acc[mi][ni][r]);
        }
      }
    __syncthreads();
    const int nloc = t >> 1;
#pragma unroll
    for (int cc = 0; cc < 4; cc++) {
      int ci = (t & 1) * 4 + cc;
      int sc = ci ^ (nloc & 7);
      uint4 v = *(const uint4*)(Tt + nloc * 64 + sc * 8);
      *(uint4*)(Cvt + (long long)(n0 - 1024 + nloc) * T_SEQ + m0 + ci * 8) = v;
    }
  }
}

// ---------------------------------------------------------------- RoPE (neox, fp64 angles), fused q+k
__global__ void rope_all(unsigned short* __restrict__ qb,
                         unsigned short* __restrict__ kb,
                         const int* __restrict__ positions) {
  const int w = threadIdx.x >> 6, d = threadIdx.x & 63;
  const int gid = blockIdx.x * 4 + w;
  unsigned short* row;
  int t;
  bool isq;
  if (gid < T_SEQ * NQH) {
    int h = gid & (NQH - 1); t = gid >> 5;
    row = qb + (size_t)t * (NQH * HDIM) + (size_t)h * HDIM;
    isq = true;
  } else {
    int g = gid - T_SEQ * NQH;
    int h = g & (NKVH - 1); t = g >> 3;
    row = kb + (size_t)t * (NKVH * HDIM) + (size_t)h * HDIM;
    isq = false;
  }
  double inv = exp2(-(double)d * 0.20762050593046014);
  double ang = (double)positions[t] * inv;
  double c = cos(ang), s = sin(ang);
  if (isq) { c *= 0.12751744416986895; s *= 0.12751744416986895; }
  float x1 = bf2f(row[d]), x2 = bf2f(row[d + 64]);
  row[d]      = f2bf((float)((double)x1 * c - (double)x2 * s));
  row[d + 64] = f2bf((float)((double)x2 * c + (double)x1 * s));
}

// ---------------------------------------------------------------- flash attention v10: GQA head-pair sharing
// grid (64,16): bx = 32-row q-tile slot, hp = head pair (2 q-heads, same kv-head).
// Wave w: head 2hp+(w&1), q-rows q0 + (w>>1)*16.. +16. Each staged K/V tile feeds
// 2x the MFMA work of v7 (staging bytes + barriers per unit halved).
// KVBLK=64 single-buffered (40KB LDS), zigzag on pair parity, XCD: kvh per XCD.
__global__ __launch_bounds__(256) void attn_kernel(const unsigned short* __restrict__ qb,
                                                   const unsigned short* __restrict__ kb,
                                                   const unsigned short* __restrict__ vt,
                                                   unsigned short* __restrict__ ab) {
  __shared__ unsigned short Ks[64 * 128];
  __shared__ unsigned short Vs[128 * 64];
  __shared__ unsigned short Ps[4][16 * 64];

  const int lin = blockIdx.y * gridDim.x + blockIdx.x;  // grid (64,16) = 1024
  const int swz = (lin & 7) * 128 + (lin >> 3);
  const int bx = swz & 63;          // q-tile slot
  const int hp = swz >> 6;          // head pair 0..15 ; XCD chunk c -> hp {2c,2c+1} -> kvh=c
  const int kvh = hp >> 1;
  const int t = threadIdx.x, lane = t & 63, w = t >> 6;
  const int l15 = lane & 15, lg = lane >> 4;
  const int head = 2 * hp + (w & 1);
  const int wr16 = (w >> 1) * 16;   // wave's row offset within the 32-row tile
  const int jt = (hp & 1) ? bx : 63 - bx;  // zigzag balance
  const int q0 = jt * 32;

  bf16x8 qf[4];
#pragma unroll
  for (int kk = 0; kk < 4; kk++)
    qf[kk] = *(const bf16x8*)(qb + (long long)(q0 + wr16 + l15) * (NQH * HDIM) +
                              head * HDIM + kk * 32 + lg * 8);

  f32x4 accO[8];
#pragma unroll
  for (int db = 0; db < 8; db++) accO[db] = (f32x4){0.f, 0.f, 0.f, 0.f};
  float mrun[4] = {-3e38f, -3e38f, -3e38f, -3e38f};
  float lrun[4] = {0.f, 0.f, 0.f, 0.f};

  const int jd = jt >> 1;    // diagonal key-tile index
  const int nt = jd + 1;
  for (int kt = 0; kt < nt; kt++) {
    __syncthreads();
#pragma unroll
    for (int s = 0; s < 4; s++) {
      int c = t + s * 256;
      int row = c >> 4, chk = c & 15;
      GLOAD16(kb + (long long)(kt * 64 + row) * (NKVH * HDIM) + kvh * HDIM +
                  ((chk ^ (row & 7)) * 8),
              (char*)Ks + (w * 64 + s * 256) * 16);
    }
#pragma unroll
    for (int s = 0; s < 4; s++) {
      int c = t + s * 256;
      int row = c >> 3, chk = c & 7;
      GLOAD16(vt + (long long)(kvh * HDIM + row) * T_SEQ + kt * 64 +
                  ((chk ^ (row & 7)) * 8),
              (char*)Vs + (w * 64 + s * 256) * 16);
    }
    __syncthreads();

    f32x4 accS[4];
#pragma unroll
    for (int kc = 0; kc < 4; kc++) accS[kc] = (f32x4){0.f, 0.f, 0.f, 0.f};
    __builtin_amdgcn_s_setprio(1);
#pragma unroll
    for (int kk = 0; kk < 4; kk++)
#pragma unroll
      for (int kc = 0; kc < 4; kc++) {
        int row = kc * 16 + l15;
        bf16x8 b = *(const bf16x8*)(Ks + row * 128 + (((kk * 4 + lg) ^ (l15 & 7)) * 8));
        accS[kc] = mfma_bf16(qf[kk], b, accS[kc]);
      }
    __builtin_amdgcn_s_setprio(0);

    // causal mask only on the diagonal key-tile
    float pm[4][4];
    if (kt == jd) {
      const int qloc = (jt & 1) * 32 + wr16 + lg * 4;  // q-row local to the 64-key frame
#pragma unroll
      for (int kc = 0; kc < 4; kc++) {
        int kcl = kc * 16 + l15;
#pragma unroll
        for (int r = 0; r < 4; r++)
          pm[kc][r] = (kcl > qloc + r) ? -3e38f : accS[kc][r];
      }
    } else {
#pragma unroll
      for (int kc = 0; kc < 4; kc++)
#pragma unroll
        for (int r = 0; r < 4; r++) pm[kc][r] = accS[kc][r];
    }

    // lane-local max; __any-gated full reduce + rescale (defer-max THR=8)
    float rm[4];
#pragma unroll
    for (int r = 0; r < 4; r++)
      rm[r] = fmaxf(fmaxf(pm[0][r], pm[1][r]), fmaxf(pm[2][r], pm[3][r]));
    int needl = 0;
#pragma unroll
    for (int r = 0; r < 4; r++) needl |= (rm[r] > mrun[r] + 8.f) ? 1 : 0;
    if (__any(needl)) {
#pragma unroll
      for (int off = 1; off < 16; off <<= 1)
#pragma unroll
        for (int r = 0; r < 4; r++) rm[r] = fmaxf(rm[r], __shfl_xor(rm[r], off, 64));
#pragma unroll
      for (int r = 0; r < 4; r++) {
        float mn = fmaxf(mrun[r], rm[r]);
        float corr = exp2f(mrun[r] - mn);
        mrun[r] = mn;
        lrun[r] *= corr;
#pragma unroll
        for (int db = 0; db < 8; db++) accO[db][r] *= corr;
      }
    }

    __bf16 pbh[4][4];
#pragma unroll
    for (int kc = 0; kc < 4; kc++)
#pragma unroll
      for (int r = 0; r < 4; r++) {
        float p = exp2f(pm[kc][r] - mrun[r]);
        lrun[r] += p;
        pbh[kc][r] = (__bf16)p;
      }

    unsigned short* Pw = &Ps[w][0];
#pragma unroll
    for (int kc = 0; kc < 4; kc++)
#pragma unroll
      for (int r = 0; r < 4; r++) {
        int prow = lg * 4 + r;
        ((__bf16*)Pw)[(prow * 64 + kc * 16 + l15) ^ ((prow & 7) << 3)] = pbh[kc][r];
      }
    asm volatile("s_waitcnt lgkmcnt(0)" ::: "memory");

    __builtin_amdgcn_s_setprio(1);
#pragma unroll
    for (int ks = 0; ks < 2; ks++) {
      bf16x8 pa = *(const bf16x8*)(Pw + ((l15 * 64 + ks * 32 + lg * 8) ^ ((l15 & 7) << 3)));
#pragma unroll
      for (int db = 0; db < 8; db++) {
        int vrow = db * 16 + l15;
        bf16x8 b = *(const bf16x8*)(Vs + vrow * 64 + (((ks * 4 + lg) ^ (vrow & 7)) * 8));
        accO[db] = mfma_bf16(pa, b, accO[db]);
      }
    }
    __builtin_amdgcn_s_setprio(0);
  }

#pragma unroll
  for (int off = 1; off < 16; off <<= 1)
#pragma unroll
    for (int r = 0; r < 4; r++) lrun[r] += __shfl_xor(lrun[r], off, 64);
#pragma unroll
  for (int db = 0; db < 8; db++)
#pragma unroll
    for (int r = 0; r < 4; r++) {
      int qr = q0 + wr16 + lg * 4 + r;
      int col = head * HDIM + db * 16 + l15;
      ((__bf16*)ab)[(long long)qr * (NQH * HDIM) + col] = (__bf16)(accO[db][r] / lrun[r]);
    }
}

// ---------------------------------------------------------------- launch
extern "C" void kernel_launch(void* const* d_in, const int* in_sizes, int n_in,
                              void* d_out, int out_size, void* d_ws, size_t ws_size,
                              hipStream_t stream) {
  const int*   positions = (const int*)d_in[0];
  const float* hs = (const float*)d_in[1];
  const float* wq = (const float*)d_in[2];
  const float* wk = (const float*)d_in[3];
  const float* wv = (const float*)d_in[4];
  const float* wo = (const float*)d_in[5];
  float* out = (float*)d_out;

  const size_t SZ_WT = (size_t)HID * HID * 2;
  const size_t SZ_HB = (size_t)T_SEQ * HID * 2;
  const size_t SZ_QB = (size_t)T_SEQ * NQH * HDIM * 2;
  const size_t SZ_KB = (size_t)T_SEQ * NKVH * HDIM * 2;
  const size_t need = SZ_WT + SZ_HB + SZ_QB + SZ_KB * 2;
  if (ws_size < need) return;  // absmax 4.625 signature

  char* p = (char*)d_ws;
  unsigned short* wt  = (unsigned short*)p; p += SZ_WT;
  unsigned short* hb  = (unsigned short*)p; p += SZ_HB;
  unsigned short* qb  = (unsigned short*)p; p += SZ_QB;
  unsigned short* kb  = (unsigned short*)p; p += SZ_KB;
  unsigned short* vtb = (unsigned short*)p; p += SZ_KB;
  unsigned short* ab  = hb;  // alias: hb dead after KV-GEMM

  prep_qw<<<8192 + 4096, 256, 0, stream>>>(hs, hb, wq, wt);
  gemm_bt<0><<<dim3((NQH * HDIM) / 128, T_SEQ / 128), 256, 0, stream>>>(hb, wt, qb, T_SEQ, NQH * HDIM, HID);

  transpose_conv_kv<<<dim3((NKVH * HDIM) / 64, HID / 64, 2), 256, 0, stream>>>(wk, wv, wt);
  gemm_kv64<<<dim3(16, 32), 256, 0, stream>>>(hb, wt, kb, vtb);

  rope_all<<<(T_SEQ * (NQH + NKVH)) / 4, 256, 0, stream>>>(qb, kb, positions);

  attn_kernel<<<dim3(64, 16), 256, 0, stream>>>(qb, kb, vtb, ab);

  transpose_conv<<<dim3(HID / 64, (NQH * HDIM) / 64), 256, 0, stream>>>(wo, wt, NQH * HDIM, HID);
  gemm_bt<2><<<dim3(HID / 128, T_SEQ / 128), 256, 0, stream>>>(ab, wt, out, T_SEQ, HID, NQH * HDIM);
}